// Round 1
// baseline (110.318 us; speedup 1.0000x reference)
//
#include <hip/hip_runtime.h>
#include <stdint.h>

#define T_ROWS 256
#define KF 4096
#define OF 11008
// grouped (dest) segment layout: [0,3712) 4-bit, [3712,3968) 6-bit, [3968,4096) 8-bit

typedef int   v4i __attribute__((ext_vector_type(4)));
typedef float v4f __attribute__((ext_vector_type(4)));

typedef const __attribute__((address_space(1))) uint8_t* gptr_t;
typedef __attribute__((address_space(3))) uint8_t* lptr_t;

// ---------------------------------------------------------------------------
// Kernel 0: build src_of[] — stable partition of source columns by segment.
// g[c] = segment of source column c (via permuted position); rank by prefix sum.
// ---------------------------------------------------------------------------
__global__ __launch_bounds__(256) void perm_k(const int* __restrict__ idx,
                                              int* __restrict__ src_of) {
    __shared__ uint8_t g[KF];
    __shared__ int cnt[3][256];
    const int t = threadIdx.x;
    for (int i = 0; i < 16; ++i) {
        int p = t * 16 + i;
        int seg = p < 3712 ? 0 : (p < 3968 ? 1 : 2);
        g[idx[p]] = (uint8_t)seg;
    }
    __syncthreads();
    int c0 = 0, c1 = 0, c2 = 0;
    for (int i = 0; i < 16; ++i) {
        int s = g[t * 16 + i];
        c0 += (s == 0); c1 += (s == 1); c2 += (s == 2);
    }
    cnt[0][t] = c0; cnt[1][t] = c1; cnt[2][t] = c2;
    __syncthreads();
    if (t < 3) {
        int run = 0;
        for (int i = 0; i < 256; ++i) { int v = cnt[t][i]; cnt[t][i] = run; run += v; }
    }
    __syncthreads();
    int off0 = cnt[0][t], off1 = 3712 + cnt[1][t], off2 = 3968 + cnt[2][t];
    for (int i = 0; i < 16; ++i) {
        int c = t * 16 + i;
        int s = g[c];
        int d = (s == 0) ? off0++ : (s == 1) ? off1++ : off2++;
        src_of[d] = c;
    }
}

// ---------------------------------------------------------------------------
// Kernel 1/2: per-row quantize into grouped layout. One block per row.
// Thread t owns dest positions [t*16, t*16+16) — entirely within one segment
// (3712 = 232*16, 256 = 16*16, 128 = 8*16).
// ---------------------------------------------------------------------------
__global__ __launch_bounds__(256) void quant_k(const float* __restrict__ src,
                                               const int* __restrict__ src_of,
                                               int8_t* __restrict__ qout,
                                               float* __restrict__ scales,
                                               int nrows) {
    __shared__ float lmax[256];
    __shared__ float sm[3];
    const int r = blockIdx.x;
    const int t = threadIdx.x;
    const int seg = t < 232 ? 0 : (t < 248 ? 1 : 2);
    const float qmax = seg == 0 ? 7.f : (seg == 1 ? 31.f : 127.f);

    int c[16];
#pragma unroll
    for (int i = 0; i < 4; ++i) {
        v4i ci = *(const v4i*)&src_of[t * 16 + i * 4];
        c[i*4+0] = ci[0]; c[i*4+1] = ci[1]; c[i*4+2] = ci[2]; c[i*4+3] = ci[3];
    }
    const float* row = src + (size_t)r * KF;
    float v[16];
    float mx = 0.f;
#pragma unroll
    for (int i = 0; i < 16; ++i) { v[i] = row[c[i]]; mx = fmaxf(mx, fabsf(v[i])); }
    lmax[t] = mx;
    __syncthreads();
    const int wv = t >> 6, ln = t & 63;
    if (wv == 0) {
        float m = fmaxf(fmaxf(lmax[ln], lmax[ln + 64]), lmax[ln + 128]);
        if (ln < 40) m = fmaxf(m, lmax[ln + 192]);
#pragma unroll
        for (int off = 32; off; off >>= 1) m = fmaxf(m, __shfl_xor(m, off));
        if (ln == 0) sm[0] = m;
    } else if (wv == 1) {
        float m = ln < 16 ? lmax[232 + ln] : 0.f;
#pragma unroll
        for (int off = 8; off; off >>= 1) m = fmaxf(m, __shfl_xor(m, off));
        if (ln == 0) sm[1] = m;
    } else if (wv == 2) {
        float m = ln < 8 ? lmax[248 + ln] : 0.f;
#pragma unroll
        for (int off = 4; off; off >>= 1) m = fmaxf(m, __shfl_xor(m, off));
        if (ln == 0) sm[2] = m;
    }
    __syncthreads();
    float s = sm[seg] / qmax;
    if (s == 0.f) s = 1.f;
    if (t == 0 || t == 232 || t == 248) scales[seg * nrows + r] = s;
    union { int8_t b[16]; v4i q; } u;
#pragma unroll
    for (int i = 0; i < 16; ++i) {
        float qv = rintf(fminf(fmaxf(v[i] / s, -qmax), qmax));  // RNE == np.round
        u.b[i] = (int8_t)qv;
    }
    *(v4i*)(qout + (size_t)r * KF + t * 16) = u.q;
}

// ---------------------------------------------------------------------------
// Kernel 3: int8 MFMA GEMM. 128x64 tile, grid 344, 4 waves (wave = 32 rows).
// Double-buffered LDS staged via global_load_lds(16B); XOR chunk swizzle
// (source-side pre-swizzle + swizzled ds_read, rule 21). Segment-boundary
// flush of i32 acc -> f32 acc with per-segment rank-1 scales.
// ---------------------------------------------------------------------------
__global__ __launch_bounds__(256, 2)
void gemm_k(const int8_t* __restrict__ qX, const int8_t* __restrict__ qW,
            const float* __restrict__ sX, const float* __restrict__ sW,
            const float* __restrict__ bias, float* __restrict__ out) {
    __shared__ __align__(16) int8_t lA[2][128 * 64];
    __shared__ __align__(16) int8_t lB[2][64 * 64];

    const int bid = blockIdx.x;
    const int swz = (bid & 7) * 43 + (bid >> 3);  // 344 % 8 == 0: bijective
    const int mb = swz & 1;
    const int nb = swz >> 1;
    const int row0 = mb * 128;
    const int col0 = nb * 64;
    const int tid = threadIdx.x;
    const int lane = tid & 63;
    const int w = tid >> 6;

    v4i iacc[2][4];
    v4f facc[2][4];
#pragma unroll
    for (int m = 0; m < 2; ++m)
#pragma unroll
        for (int n = 0; n < 4; ++n) {
            iacc[m][n][0]=0; iacc[m][n][1]=0; iacc[m][n][2]=0; iacc[m][n][3]=0;
            facc[m][n][0]=0.f; facc[m][n][1]=0.f; facc[m][n][2]=0.f; facc[m][n][3]=0.f;
        }

    // staging rows (tile-local) for this lane: 4 lanes cover one row's 64B
    const int ar0 = (w * 2 + 0) * 16 + (lane >> 2);
    const int ar1 = (w * 2 + 1) * 16 + (lane >> 2);
    const int br  = w * 16 + (lane >> 2);
    const int sc0 = (lane & 3) ^ (ar0 & 3);
    const int sc1 = (lane & 3) ^ (ar1 & 3);
    const int scb = (lane & 3) ^ (br & 3);

    auto stage = [&](int bf, int kstep) {
        const int k0 = kstep * 64;
        {
            const uint8_t* src = (const uint8_t*)qX + (size_t)(row0 + ar0) * KF + k0 + sc0 * 16;
            __builtin_amdgcn_global_load_lds((gptr_t)src, (lptr_t)&lA[bf][(w * 2 + 0) * 1024], 16, 0, 0);
        }
        {
            const uint8_t* src = (const uint8_t*)qX + (size_t)(row0 + ar1) * KF + k0 + sc1 * 16;
            __builtin_amdgcn_global_load_lds((gptr_t)src, (lptr_t)&lA[bf][(w * 2 + 1) * 1024], 16, 0, 0);
        }
        {
            const uint8_t* src = (const uint8_t*)qW + (size_t)(col0 + br) * KF + k0 + scb * 16;
            __builtin_amdgcn_global_load_lds((gptr_t)src, (lptr_t)&lB[bf][w * 1024], 16, 0, 0);
        }
    };

    auto flush = [&](int seg) {
#pragma unroll
        for (int m = 0; m < 2; ++m) {
            float sa[4];
#pragma unroll
            for (int rr = 0; rr < 4; ++rr)
                sa[rr] = sX[seg * T_ROWS + row0 + w * 32 + m * 16 + ((lane >> 4) << 2) + rr];
#pragma unroll
            for (int n = 0; n < 4; ++n) {
                const float sb = sW[seg * OF + col0 + n * 16 + (lane & 15)];
#pragma unroll
                for (int rr = 0; rr < 4; ++rr) {
                    facc[m][n][rr] += (float)iacc[m][n][rr] * (sa[rr] * sb);
                    iacc[m][n][rr] = 0;
                }
            }
        }
    };

    stage(0, 0);
    asm volatile("s_waitcnt vmcnt(0)" ::: "memory");
    __builtin_amdgcn_s_barrier();
    int cur = 0;
    for (int t = 0; t < 64; ++t) {
        if (t < 63) stage(cur ^ 1, t + 1);
        v4i a[2], b[4];
        const int kg = lane >> 4;
#pragma unroll
        for (int m = 0; m < 2; ++m) {
            const int row = w * 32 + m * 16 + (lane & 15);
            a[m] = *(const v4i*)&lA[cur][row * 64 + ((kg ^ (row & 3)) << 4)];
        }
#pragma unroll
        for (int n = 0; n < 4; ++n) {
            const int row = n * 16 + (lane & 15);
            b[n] = *(const v4i*)&lB[cur][row * 64 + ((kg ^ (row & 3)) << 4)];
        }
        asm volatile("s_waitcnt lgkmcnt(0)" ::: "memory");
        __builtin_amdgcn_sched_barrier(0);
#pragma unroll
        for (int m = 0; m < 2; ++m)
#pragma unroll
            for (int n = 0; n < 4; ++n)
                iacc[m][n] = __builtin_amdgcn_mfma_i32_16x16x64_i8(a[m], b[n], iacc[m][n], 0, 0, 0);
        if (t == 57) flush(0);        // end of 4-bit segment (58 steps * 64)
        else if (t == 61) flush(1);   // end of 6-bit segment
        asm volatile("s_waitcnt vmcnt(0)" ::: "memory");
        __builtin_amdgcn_s_barrier();
        cur ^= 1;
    }
    flush(2);                          // 8-bit segment

#pragma unroll
    for (int m = 0; m < 2; ++m)
#pragma unroll
        for (int n = 0; n < 4; ++n) {
            const int colg = col0 + n * 16 + (lane & 15);
            const float bv = bias[colg];
#pragma unroll
            for (int rr = 0; rr < 4; ++rr) {
                const int rowg = row0 + w * 32 + m * 16 + ((lane >> 4) << 2) + rr;
                out[(size_t)rowg * OF + colg] = facc[m][n][rr] + bv;
            }
        }
}

// ---------------------------------------------------------------------------
// workspace layout (bytes):
//   qX      @ 0          :  1,048,576
//   qW      @ 1,048,576  : 45,088,768
//   sX      @ 46,137,344 :      3,072   (3 x 256 f32)
//   sW      @ 46,140,416 :    132,096   (3 x 11008 f32)
//   src_of  @ 46,272,512 :     16,384   (4096 i32)
// total ~46.3 MB
// ---------------------------------------------------------------------------
extern "C" void kernel_launch(void* const* d_in, const int* in_sizes, int n_in,
                              void* d_out, int out_size, void* d_ws, size_t ws_size,
                              hipStream_t stream) {
    const float* x    = (const float*)d_in[0];
    const float* W    = (const float*)d_in[1];
    const float* bias = (const float*)d_in[2];
    const int*   ridx = (const int*)d_in[3];
    float* out = (float*)d_out;

    uint8_t* ws = (uint8_t*)d_ws;
    int8_t* qX = (int8_t*)ws;
    int8_t* qW = (int8_t*)(ws + 1048576);
    float*  sX = (float*)(ws + 46137344);
    float*  sW = (float*)(ws + 46140416);
    int* src_of = (int*)(ws + 46272512);

    perm_k<<<1, 256, 0, stream>>>(ridx, src_of);
    quant_k<<<T_ROWS, 256, 0, stream>>>(x, src_of, qX, sX, T_ROWS);
    quant_k<<<OF, 256, 0, stream>>>(W, src_of, qW, sW, OF);
    gemm_k<<<344, 256, 0, stream>>>(qX, qW, sX, sW, bias, out);
}

// Round 2
// 79.342 us; speedup vs baseline: 1.3904x; 1.3904x over previous
//
#include <hip/hip_runtime.h>
#include <stdint.h>

#define T_ROWS 256
#define KF 4096
#define OF 11008
// grouped (dest) segment layout: [0,3712) 4-bit, [3712,3968) 6-bit, [3968,4096) 8-bit

typedef int   v4i __attribute__((ext_vector_type(4)));
typedef float v4f __attribute__((ext_vector_type(4)));

typedef const __attribute__((address_space(1))) uint8_t* gptr_t;
typedef __attribute__((address_space(3))) uint8_t* lptr_t;

// ---------------------------------------------------------------------------
// Kernel 0: build src_of[] — stable partition of source columns by segment.
// ---------------------------------------------------------------------------
__global__ __launch_bounds__(256) void perm_k(const int* __restrict__ idx,
                                              int* __restrict__ src_of) {
    __shared__ uint8_t g[KF];
    __shared__ int cnt[3][256];
    const int t = threadIdx.x;
    for (int i = 0; i < 16; ++i) {
        int p = t * 16 + i;
        int seg = p < 3712 ? 0 : (p < 3968 ? 1 : 2);
        g[idx[p]] = (uint8_t)seg;
    }
    __syncthreads();
    int c0 = 0, c1 = 0, c2 = 0;
    for (int i = 0; i < 16; ++i) {
        int s = g[t * 16 + i];
        c0 += (s == 0); c1 += (s == 1); c2 += (s == 2);
    }
    cnt[0][t] = c0; cnt[1][t] = c1; cnt[2][t] = c2;
    __syncthreads();
    if (t < 3) {
        int run = 0;
        for (int i = 0; i < 256; ++i) { int v = cnt[t][i]; cnt[t][i] = run; run += v; }
    }
    __syncthreads();
    int off0 = cnt[0][t], off1 = 3712 + cnt[1][t], off2 = 3968 + cnt[2][t];
    for (int i = 0; i < 16; ++i) {
        int c = t * 16 + i;
        int s = g[c];
        int d = (s == 0) ? off0++ : (s == 1) ? off1++ : off2++;
        src_of[d] = c;
    }
}

// ---------------------------------------------------------------------------
// Kernel 1: per-row quantize (x and W in one grid). One block per row.
// Row staged to LDS with coalesced float4 loads; permutation gather resolved
// in LDS. Thread t owns dest positions [t*16, t*16+16) — single segment each
// (3712 = 232*16, 256 = 16*16, 128 = 8*16).
// ---------------------------------------------------------------------------
__global__ __launch_bounds__(256) void quant_k(const float* __restrict__ x,
                                               const float* __restrict__ W,
                                               const int* __restrict__ src_of,
                                               int8_t* __restrict__ qX,
                                               int8_t* __restrict__ qW,
                                               float* __restrict__ sX,
                                               float* __restrict__ sW) {
    __shared__ float rowbuf[KF];
    __shared__ float lmax[256];
    __shared__ float sm[3];
    const int b = blockIdx.x;
    const int t = threadIdx.x;
    const float* src; int8_t* qout; float* scales; int r; int nrows;
    if (b < T_ROWS) { src = x; qout = qX; scales = sX; r = b; nrows = T_ROWS; }
    else           { src = W; qout = qW; scales = sW; r = b - T_ROWS; nrows = OF; }
    const float* row = src + (size_t)r * KF;

    // coalesced stage: 4 x float4 per thread
#pragma unroll
    for (int i = 0; i < 4; ++i) {
        v4f v = *(const v4f*)(row + i * 1024 + t * 4);
        *(v4f*)&rowbuf[i * 1024 + t * 4] = v;
    }

    const int seg = t < 232 ? 0 : (t < 248 ? 1 : 2);
    const float qmax = seg == 0 ? 7.f : (seg == 1 ? 31.f : 127.f);
    int c[16];
#pragma unroll
    for (int i = 0; i < 4; ++i) {
        v4i ci = *(const v4i*)&src_of[t * 16 + i * 4];
        c[i*4+0] = ci[0]; c[i*4+1] = ci[1]; c[i*4+2] = ci[2]; c[i*4+3] = ci[3];
    }
    __syncthreads();

    float v[16];
    float mx = 0.f;
#pragma unroll
    for (int i = 0; i < 16; ++i) { v[i] = rowbuf[c[i]]; mx = fmaxf(mx, fabsf(v[i])); }
    lmax[t] = mx;
    __syncthreads();
    const int wv = t >> 6, ln = t & 63;
    if (wv == 0) {
        float m = fmaxf(fmaxf(lmax[ln], lmax[ln + 64]), lmax[ln + 128]);
        if (ln < 40) m = fmaxf(m, lmax[ln + 192]);
#pragma unroll
        for (int off = 32; off; off >>= 1) m = fmaxf(m, __shfl_xor(m, off));
        if (ln == 0) sm[0] = m;
    } else if (wv == 1) {
        float m = ln < 16 ? lmax[232 + ln] : 0.f;
#pragma unroll
        for (int off = 8; off; off >>= 1) m = fmaxf(m, __shfl_xor(m, off));
        if (ln == 0) sm[1] = m;
    } else if (wv == 2) {
        float m = ln < 8 ? lmax[248 + ln] : 0.f;
#pragma unroll
        for (int off = 4; off; off >>= 1) m = fmaxf(m, __shfl_xor(m, off));
        if (ln == 0) sm[2] = m;
    }
    __syncthreads();
    float s = sm[seg] / qmax;
    if (s == 0.f) s = 1.f;
    if (t == 0 || t == 232 || t == 248) scales[seg * nrows + r] = s;
    union { int8_t bb[16]; v4i q; } u;
#pragma unroll
    for (int i = 0; i < 16; ++i) {
        float qv = rintf(fminf(fmaxf(v[i] / s, -qmax), qmax));  // RNE == np.round
        u.bb[i] = (int8_t)qv;
    }
    *(v4i*)(qout + (size_t)r * KF + t * 16) = u.q;
}

// ---------------------------------------------------------------------------
// Kernel 2: int8 MFMA GEMM. 128x64 tile, grid 344, 4 waves (wave = 32x64 out).
// BK=128, 3-buffer LDS pipeline with counted vmcnt(6) (T4) so prefetch loads
// stay in flight across barriers. XOR chunk swizzle over 8 chunks, applied
// source-side at stage and at ds_read (both-sides rule).
// ---------------------------------------------------------------------------
__global__ __launch_bounds__(256, 2)
void gemm_k(const int8_t* __restrict__ qX, const int8_t* __restrict__ qW,
            const float* __restrict__ sX, const float* __restrict__ sW,
            const float* __restrict__ bias, float* __restrict__ out) {
    __shared__ __align__(16) int8_t lA[3][128 * 128];
    __shared__ __align__(16) int8_t lB[3][64 * 128];

    const int bid = blockIdx.x;
    const int swz = (bid & 7) * 43 + (bid >> 3);  // 344 = 8*43: bijective
    const int mb = swz & 1;
    const int nb = swz >> 1;
    const int row0 = mb * 128;
    const int col0 = nb * 64;
    const int tid = threadIdx.x;
    const int lane = tid & 63;
    const int w = tid >> 6;
    const int lr = lane >> 3;   // 0..7 (staging row within wave's 8-row slab)
    const int lc = lane & 7;    // 0..7 (staging 16B chunk)

    v4i iacc[2][4];
    v4f facc[2][4];
#pragma unroll
    for (int m = 0; m < 2; ++m)
#pragma unroll
        for (int n = 0; n < 4; ++n) {
            iacc[m][n][0]=0; iacc[m][n][1]=0; iacc[m][n][2]=0; iacc[m][n][3]=0;
            facc[m][n][0]=0.f; facc[m][n][1]=0.f; facc[m][n][2]=0.f; facc[m][n][3]=0.f;
        }

    // Each wave stages 8 rows (1 KB) per call: lane -> row lr, chunk lc.
    // Source chunk pre-swizzled by ^(row&7) = ^lr; LDS dest linear.
    auto stage = [&](int bf, int kstep) {
        const int k0 = kstep * 128;
        const int sc = (lc ^ lr) << 4;
#pragma unroll
        for (int j = 0; j < 4; ++j) {
            const int row = j * 32 + w * 8;
            const uint8_t* src = (const uint8_t*)qX + (size_t)(row0 + row + lr) * KF + k0 + sc;
            __builtin_amdgcn_global_load_lds((gptr_t)src, (lptr_t)&lA[bf][row * 128], 16, 0, 0);
        }
#pragma unroll
        for (int j = 0; j < 2; ++j) {
            const int row = j * 32 + w * 8;
            const uint8_t* src = (const uint8_t*)qW + (size_t)(col0 + row + lr) * KF + k0 + sc;
            __builtin_amdgcn_global_load_lds((gptr_t)src, (lptr_t)&lB[bf][row * 128], 16, 0, 0);
        }
    };

    auto flush = [&](int seg) {
#pragma unroll
        for (int m = 0; m < 2; ++m) {
            float sa[4];
#pragma unroll
            for (int rr = 0; rr < 4; ++rr)
                sa[rr] = sX[seg * T_ROWS + row0 + w * 32 + m * 16 + ((lane >> 4) << 2) + rr];
#pragma unroll
            for (int n = 0; n < 4; ++n) {
                const float sb = sW[seg * OF + col0 + n * 16 + (lane & 15)];
#pragma unroll
                for (int rr = 0; rr < 4; ++rr) {
                    facc[m][n][rr] += (float)iacc[m][n][rr] * (sa[rr] * sb);
                    iacc[m][n][rr] = 0;
                }
            }
        }
    };

    stage(0, 0);
    stage(1, 1);
    asm volatile("s_waitcnt vmcnt(6)" ::: "memory");
    __builtin_amdgcn_s_barrier();

    int cur = 0;
    for (int t = 0; t < 32; ++t) {
        if (t < 30) stage((t + 2) % 3, t + 2);   // prefetch depth 2
        v4i a[2][2], b2[4][2];
        const int kg = lane >> 4;                 // 0..3: 16B chunk within K=64 slice
#pragma unroll
        for (int m = 0; m < 2; ++m) {
            const int row = w * 32 + m * 16 + (lane & 15);
#pragma unroll
            for (int kk = 0; kk < 2; ++kk) {
                const int ch = (kk * 4 + kg) ^ (row & 7);
                a[m][kk] = *(const v4i*)&lA[cur][row * 128 + ch * 16];
            }
        }
#pragma unroll
        for (int n = 0; n < 4; ++n) {
            const int row = n * 16 + (lane & 15);
#pragma unroll
            for (int kk = 0; kk < 2; ++kk) {
                const int ch = (kk * 4 + kg) ^ (row & 7);
                b2[n][kk] = *(const v4i*)&lB[cur][row * 128 + ch * 16];
            }
        }
        asm volatile("s_waitcnt lgkmcnt(0)" ::: "memory");
        __builtin_amdgcn_sched_barrier(0);
#pragma unroll
        for (int kk = 0; kk < 2; ++kk)
#pragma unroll
            for (int m = 0; m < 2; ++m)
#pragma unroll
                for (int n = 0; n < 4; ++n)
                    iacc[m][n] = __builtin_amdgcn_mfma_i32_16x16x64_i8(a[m][kk], b2[n][kk], iacc[m][n], 0, 0, 0);
        // segment boundaries: 3712 B = step 28 end; 3968 B = step 30 end
        if (t == 28) flush(0);
        else if (t == 30) flush(1);
        if (t < 30) {
            asm volatile("s_waitcnt vmcnt(6)" ::: "memory");  // k=t+1 done; k=t+2 in flight
            __builtin_amdgcn_s_barrier();
        } else if (t == 30) {
            asm volatile("s_waitcnt vmcnt(0)" ::: "memory");  // drain last buffer
            __builtin_amdgcn_s_barrier();
        }
        cur = (cur == 2) ? 0 : cur + 1;
    }
    flush(2);

#pragma unroll
    for (int m = 0; m < 2; ++m)
#pragma unroll
        for (int n = 0; n < 4; ++n) {
            const int colg = col0 + n * 16 + (lane & 15);
            const float bv = bias[colg];
#pragma unroll
            for (int rr = 0; rr < 4; ++rr) {
                const int rowg = row0 + w * 32 + m * 16 + ((lane >> 4) << 2) + rr;
                out[(size_t)rowg * OF + colg] = facc[m][n][rr] + bv;
            }
        }
}

// ---------------------------------------------------------------------------
// workspace layout (bytes):
//   qX      @ 0          :  1,048,576
//   qW      @ 1,048,576  : 45,088,768
//   sX      @ 46,137,344 :      3,072   (3 x 256 f32)
//   sW      @ 46,140,416 :    132,096   (3 x 11008 f32)
//   src_of  @ 46,272,512 :     16,384   (4096 i32)
// ---------------------------------------------------------------------------
extern "C" void kernel_launch(void* const* d_in, const int* in_sizes, int n_in,
                              void* d_out, int out_size, void* d_ws, size_t ws_size,
                              hipStream_t stream) {
    const float* x    = (const float*)d_in[0];
    const float* W    = (const float*)d_in[1];
    const float* bias = (const float*)d_in[2];
    const int*   ridx = (const int*)d_in[3];
    float* out = (float*)d_out;

    uint8_t* ws = (uint8_t*)d_ws;
    int8_t* qX = (int8_t*)ws;
    int8_t* qW = (int8_t*)(ws + 1048576);
    float*  sX = (float*)(ws + 46137344);
    float*  sW = (float*)(ws + 46140416);
    int* src_of = (int*)(ws + 46272512);

    perm_k<<<1, 256, 0, stream>>>(ridx, src_of);
    quant_k<<<T_ROWS + OF, 256, 0, stream>>>(x, W, src_of, qX, qW, sX, sW);
    gemm_k<<<344, 256, 0, stream>>>(qX, qW, sX, sW, bias, out);
}